// Round 17
// baseline (323.207 us; speedup 1.0000x reference)
//
#include <hip/hip_runtime.h>

#define ALPHA 0.2f
#define EPS 1e-16f

static constexpr int F_IN = 256;
static constexpr int F_OUT = 128;
static constexpr int HEADS = 4;
static constexpr int COLS = HEADS * F_OUT; // 512
static constexpr int NCH = 64;             // edge chunks in counting sort

typedef __bf16 bf16x8 __attribute__((ext_vector_type(8)));
typedef float f32x4 __attribute__((ext_vector_type(4)));

static __device__ __forceinline__ unsigned short f2bf(float f) {
  unsigned int u = __float_as_uint(f);
  unsigned int r = (u + 0x7FFFu + ((u >> 16) & 1u)) >> 16;  // RN-even
  return (unsigned short)r;
}
static __device__ __forceinline__ float bf_lo(unsigned int u) {
  return __uint_as_float(u << 16);
}
static __device__ __forceinline__ float bf_hi(unsigned int u) {
  return __uint_as_float(u & 0xFFFF0000u);
}
static __device__ __forceinline__ void cvt8(const float4& p0, const float4& p1, bf16x8& v) {
  v[0] = (__bf16)p0.x; v[1] = (__bf16)p0.y; v[2] = (__bf16)p0.z; v[3] = (__bf16)p0.w;
  v[4] = (__bf16)p1.x; v[5] = (__bf16)p1.y; v[6] = (__bf16)p1.z; v[7] = (__bf16)p1.w;
}

// ---------------- K-merged: CSR stage (blocks < Cb) + GEMM chunk (rest) -------
// mode 0: range-split LDS histogram  (256 role blocks = 4 ranges x 64 chunks)
// mode 1: colsum over 64 chunk-hists + block-local scan (nscan role blocks)
// mode 2: carry scan -> off                             (nscan role blocks)
// mode 3: absolute slot bases base32[ec][s]             (nscan role blocks)
// GEMM: 128x128 MFMA, f32 A/W cast-in-staging, fused score + int8 quant epilogues.
// rec[n] (32B): bytes 0..15 = sdst (4 f32); bytes 16..31 = 8 bf16 scales.
// Hq row layout (per 64-col block b): u32 at byte 64b+4k holds cols {0,16,32,48}+k.
__global__ __launch_bounds__(256) void k_merged(int mode, int Cb, int start, int len,
    const float* __restrict__ A, const float* __restrict__ Wf,
    unsigned char* __restrict__ Hq, unsigned char* __restrict__ rec,
    float* __restrict__ ssrc, const float* __restrict__ Av, int N,
    const int* __restrict__ src, unsigned short* __restrict__ bcnt,
    int* __restrict__ cnt, int* __restrict__ bsum, int* __restrict__ off,
    unsigned int* __restrict__ base32, int E, int RNG, int Npad, int nscan) {
  __shared__ union {
    unsigned int bins[6272];                 // 25088 B (RNG <= 12544)
    struct { __bf16 As[128][40]; __bf16 Bs[128][40]; float sS[128]; float sD[128]; } g;
    int ws[4];
    int sbuf[256];
  } u;
  const int t = threadIdx.x;

  if ((int)blockIdx.x >= Cb) {
    // ================= GEMM role =================
    const int j = (int)blockIdx.x - Cb;
    const int q8 = len >> 3, r8 = len & 7;
    const int x = j & 7, ii = j >> 3;
    const int p = start + ((x < r8) ? x * (q8 + 1) + ii
                                    : r8 * (q8 + 1) + (x - r8) * q8 + ii);
    const int by = p >> 2;                   // row-tile
    const int bx = p & 3;                    // 128-col block == head
    const int w = t >> 6, l = t & 63;
    const int wr = w >> 1, wc = w & 1;       // 2x2 wave grid, each 64x64
    const int m0 = by << 7, n0 = bx << 7;
    const int lr = t >> 1, seg16 = (t & 1) << 4;
    int ar = m0 + lr; if (ar >= N) ar = N - 1;
    const float* Ap = A + (size_t)ar * F_IN + seg16;
    const float* Wp = Wf + (size_t)(n0 + lr) * F_IN + seg16;
    f32x4 acc[4][4] = {};
    for (int k0 = 0; k0 < F_IN; k0 += 32) {
      const float4 f0 = *(const float4*)(Ap + k0);
      const float4 f1 = *(const float4*)(Ap + k0 + 4);
      const float4 f2 = *(const float4*)(Ap + k0 + 8);
      const float4 f3 = *(const float4*)(Ap + k0 + 12);
      const float4 g0 = *(const float4*)(Wp + k0);
      const float4 g1 = *(const float4*)(Wp + k0 + 4);
      const float4 g2 = *(const float4*)(Wp + k0 + 8);
      const float4 g3 = *(const float4*)(Wp + k0 + 12);
      bf16x8 v0, v1, u0, u1;
      cvt8(f0, f1, v0); cvt8(f2, f3, v1);
      cvt8(g0, g1, u0); cvt8(g2, g3, u1);
      __syncthreads();
      *(bf16x8*)&u.g.As[lr][seg16] = v0;  *(bf16x8*)&u.g.As[lr][seg16 + 8] = v1;
      *(bf16x8*)&u.g.Bs[lr][seg16] = u0;  *(bf16x8*)&u.g.Bs[lr][seg16 + 8] = u1;
      __syncthreads();
      const int kb = (l >> 4) << 3;
      bf16x8 af[4], bf_[4];
#pragma unroll
      for (int mi = 0; mi < 4; ++mi)
        af[mi] = *(const bf16x8*)&u.g.As[(wr << 6) + (mi << 4) + (l & 15)][kb];
#pragma unroll
      for (int ni = 0; ni < 4; ++ni)
        bf_[ni] = *(const bf16x8*)&u.g.Bs[(wc << 6) + (ni << 4) + (l & 15)][kb];
#pragma unroll
      for (int mi = 0; mi < 4; ++mi)
#pragma unroll
        for (int ni = 0; ni < 4; ++ni)
          acc[mi][ni] = __builtin_amdgcn_mfma_f32_16x16x32_bf16(af[mi], bf_[ni], acc[mi][ni], 0, 0, 0);
    }
    // ---- score epilogue ----
    {
      float as_[4], ad_[4];
#pragma unroll
      for (int ni = 0; ni < 4; ++ni) {
        const int f = (wc << 6) + (ni << 4) + (l & 15);
        as_[ni] = Av[bx * 256 + f];
        ad_[ni] = Av[bx * 256 + 128 + f];
      }
#pragma unroll
      for (int mi = 0; mi < 4; ++mi)
#pragma unroll
        for (int r = 0; r < 4; ++r) {
          float ds_ = 0.f, dd_ = 0.f;
#pragma unroll
          for (int ni = 0; ni < 4; ++ni) {
            ds_ = fmaf(acc[mi][ni][r], as_[ni], ds_);
            dd_ = fmaf(acc[mi][ni][r], ad_[ni], dd_);
          }
#pragma unroll
          for (int m = 1; m < 16; m <<= 1) {
            ds_ += __shfl_xor(ds_, m);
            dd_ += __shfl_xor(dd_, m);
          }
          if (wc == 0 && (l & 15) == 0) {
            const int rl = (wr << 6) + (mi << 4) + ((l >> 4) << 2) + r;
            u.g.sS[rl] = ds_; u.g.sD[rl] = dd_;
          }
        }
      __syncthreads();
      if (wc == 1) {
#pragma unroll
        for (int mi = 0; mi < 4; ++mi)
#pragma unroll
          for (int r = 0; r < 4; ++r) {
            float ds_ = 0.f, dd_ = 0.f;
#pragma unroll
            for (int ni = 0; ni < 4; ++ni) {
              ds_ = fmaf(acc[mi][ni][r], as_[ni], ds_);
              dd_ = fmaf(acc[mi][ni][r], ad_[ni], dd_);
            }
#pragma unroll
            for (int m = 1; m < 16; m <<= 1) {
              ds_ += __shfl_xor(ds_, m);
              dd_ += __shfl_xor(dd_, m);
            }
            if ((l & 15) == 0) {
              const int rl = (wr << 6) + (mi << 4) + ((l >> 4) << 2) + r;
              const int row = m0 + rl;
              if (row < N) {
                ssrc[row * 4 + bx] = u.g.sS[rl] + ds_;
                *(float*)&rec[(size_t)row * 32 + (bx << 2)] = u.g.sD[rl] + dd_;
              }
            }
          }
      }
    }
    // ---- quant epilogue ----
    const int bxg = (bx << 1) + wc;
#pragma unroll
    for (int mi = 0; mi < 4; ++mi)
#pragma unroll
      for (int r = 0; r < 4; ++r) {
        float mx = 0.f;
#pragma unroll
        for (int ni = 0; ni < 4; ++ni) mx = fmaxf(mx, fabsf(acc[mi][ni][r]));
#pragma unroll
        for (int m = 1; m < 16; m <<= 1) mx = fmaxf(mx, __shfl_xor(mx, m));
        const int row = m0 + (wr << 6) + (mi << 4) + ((l >> 4) << 2) + r;
        if (row < N) {
          const float inv = (mx > 0.f) ? 127.f / mx : 0.f;
          if ((l & 15) == 0)
            *(unsigned short*)&rec[(size_t)row * 32 + 16 + (bxg << 1)] = f2bf(mx * (1.f / 127.f));
          unsigned int pk = 0;
#pragma unroll
          for (int ni = 0; ni < 4; ++ni) {
            float tq = fminf(fmaxf(rintf(acc[mi][ni][r] * inv), -127.f), 127.f);
            pk |= ((unsigned int)(((int)tq + 128) & 255)) << (8 * ni);
          }
          *(unsigned int*)&Hq[(size_t)row * 512 + (bxg << 6) + ((l & 15) << 2)] = pk;
        }
      }
    return;
  }

  // ================= CSR roles =================
  if (mode == 0) {
    // range-split LDS histogram: block = (rq, ec)
    const int ec = blockIdx.x & (NCH - 1), rq = blockIdx.x >> 6;
    const int r0 = rq * RNG;
    const int nw = RNG >> 1;
    for (int jj = t; jj < nw; jj += 256) u.bins[jj] = 0u;
    __syncthreads();
    const int CE = (E + NCH - 1) / NCH;
    const int i0 = ec * CE, i1 = min(E, i0 + CE);
    for (int i = i0 + t; i < i1; i += 256) {
      const unsigned us = (unsigned)(src[i] - r0);
      if (us < (unsigned)RNG) atomicAdd(&u.bins[us >> 1], 1u << ((us & 1) << 4));
    }
    __syncthreads();
    uint4* dv = (uint4*)(bcnt + (size_t)ec * Npad + r0);   // 16B-aligned (RNG%8==0)
    const uint4* sv = (const uint4*)u.bins;
    const int nv = RNG >> 3;
    for (int m = t; m < nv; m += 256) dv[m] = sv[m];
  } else if (mode == 1) {
    // colsum over NCH chunk-hists + block-local inclusive scan (256/block)
    const int g = blockIdx.x * 256 + t;
    const int lane = t & 63, w = t >> 6;
    int v = 0;
    if (g < N) {
#pragma unroll 8
      for (int b = 0; b < NCH; ++b) v += bcnt[(size_t)b * Npad + g];
    }
#pragma unroll
    for (int o = 1; o < 64; o <<= 1) {
      const int y = __shfl_up(v, o);
      if (lane >= o) v += y;
    }
    if (lane == 63) u.ws[w] = v;
    __syncthreads();
    if (t == 0) {
      int s = 0;
#pragma unroll
      for (int k = 0; k < 4; ++k) { s += u.ws[k]; u.ws[k] = s; }
    }
    __syncthreads();
    v += (w > 0) ? u.ws[w - 1] : 0;
    if (g < N) cnt[g] = v;
    if (t == 255) bsum[blockIdx.x] = v;
  } else if (mode == 2) {
    // carry scan of bsum (nscan entries) + off
    if (t < 64) {
      int carry = 0;
      for (int base = 0; base < nscan; base += 64) {
        int v = (base + t < nscan) ? bsum[base + t] : 0;
#pragma unroll
        for (int o = 1; o < 64; o <<= 1) {
          const int y = __shfl_up(v, o);
          if (t >= o) v += y;
        }
        v += carry;
        if (base + t < nscan) u.sbuf[base + t] = v;
        carry = __shfl(v, 63);
      }
    }
    __syncthreads();
    const int g = blockIdx.x * 256 + t;
    if (g == 0) off[0] = 0;
    if (g < N) off[g + 1] = cnt[g] + (blockIdx.x ? u.sbuf[blockIdx.x - 1] : 0);
  } else {
    // absolute slot bases
    const int s = blockIdx.x * 256 + t;
    if (s < N) {
      unsigned int run = (unsigned int)off[s];
#pragma unroll 8
      for (int b = 0; b < NCH; ++b) {
        const size_t idx = (size_t)b * Npad + s;
        const unsigned int v = bcnt[idx];
        base32[idx] = run;
        run += v;
      }
    }
  }
}

// ---------------- K-place: re-histogram + direct placement (no global atomics)
__global__ __launch_bounds__(256) void k_place(const int* __restrict__ src,
                                               const int* __restrict__ dst,
                                               const unsigned int* __restrict__ base32,
                                               unsigned short* __restrict__ csr,
                                               int E, int RNG, int Npad) {
  __shared__ unsigned int bins[6272];
  const int ec = blockIdx.x & (NCH - 1), rq = blockIdx.x >> 6;
  const int r0 = rq * RNG, t = threadIdx.x;
  const int nw = RNG >> 1;
  for (int jj = t; jj < nw; jj += 256) bins[jj] = 0u;
  __syncthreads();
  const unsigned int* brow = base32 + (size_t)ec * Npad;
  const int CE = (E + NCH - 1) / NCH;
  const int i0 = ec * CE, i1 = min(E, i0 + CE);
  for (int i = i0 + t; i < i1; i += 256) {
    const int s = src[i];
    const unsigned us = (unsigned)(s - r0);
    if (us < (unsigned)RNG) {
      const unsigned int old = atomicAdd(&bins[us >> 1], 1u << ((us & 1) << 4));
      const int local = (old >> ((us & 1) << 4)) & 0xffff;
      csr[brow[s] + local] = (unsigned short)dst[i];
    }
  }
}

// ---------------- K4: fused softmax + SpMM, excess-128 int8 -------------------
__global__ __launch_bounds__(256) void k_spmm(const uint2* __restrict__ Hq2,
    const float4* __restrict__ ssrc4, const unsigned char* __restrict__ rec,
    const int* __restrict__ off, const unsigned short* __restrict__ csr_dst,
    const float* __restrict__ bias, float* __restrict__ out, int N) {
  __shared__ float wbuf[4][8][72];
  __shared__ int   ibuf[4][64];
  const int wv = threadIdx.x >> 6;
  const int lane = threadIdx.x & 63;
  const int n = (blockIdx.x << 2) + wv;
  if (n >= N) return;
  const int hg = lane >> 4;
  const int b8 = lane >> 3;
  const float4 ss4 = ssrc4[n];
  float den4[4] = {};
  float acc[8] = {};
  float sw = 0.f;
  const int beg = off[n], end = off[n + 1];
  for (int c0 = beg; c0 < end; c0 += 64) {
    const int cnt = min(64, end - c0);
    if (lane < cnt) {
      const int d = csr_dst[c0 + lane];
      ibuf[wv][lane] = d << 6;
      const float4 sd4 = *(const float4*)&rec[(size_t)d * 32];
      const uint4  sc  = *(const uint4*)&rec[(size_t)d * 32 + 16];
      float e0 = ss4.x + sd4.x; e0 = fmaxf(e0, ALPHA * e0);
      float e1 = ss4.y + sd4.y; e1 = fmaxf(e1, ALPHA * e1);
      float e2 = ss4.z + sd4.z; e2 = fmaxf(e2, ALPHA * e2);
      float e3 = ss4.w + sd4.w; e3 = fmaxf(e3, ALPHA * e3);
      const float w0 = __expf(e0), w1 = __expf(e1), w2 = __expf(e2), w3 = __expf(e3);
      den4[0] += w0; den4[1] += w1; den4[2] += w2; den4[3] += w3;
      wbuf[wv][0][lane] = w0 * bf_lo(sc.x); wbuf[wv][1][lane] = w0 * bf_hi(sc.x);
      wbuf[wv][2][lane] = w1 * bf_lo(sc.y); wbuf[wv][3][lane] = w1 * bf_hi(sc.y);
      wbuf[wv][4][lane] = w2 * bf_lo(sc.z); wbuf[wv][5][lane] = w2 * bf_hi(sc.z);
      wbuf[wv][6][lane] = w3 * bf_lo(sc.w); wbuf[wv][7][lane] = w3 * bf_hi(sc.w);
    }
#pragma unroll 8
    for (int j = 0; j < cnt; ++j) {
      const float wgt = wbuf[wv][b8][j];
      const int db = ibuf[wv][j];
      const uint2 q = Hq2[db + lane];
      sw += wgt;
      acc[0] = fmaf(wgt, (float)(q.x & 0xffu),         acc[0]);
      acc[1] = fmaf(wgt, (float)((q.x >> 8) & 0xffu),  acc[1]);
      acc[2] = fmaf(wgt, (float)((q.x >> 16) & 0xffu), acc[2]);
      acc[3] = fmaf(wgt, (float)(q.x >> 24),           acc[3]);
      acc[4] = fmaf(wgt, (float)(q.y & 0xffu),         acc[4]);
      acc[5] = fmaf(wgt, (float)((q.y >> 8) & 0xffu),  acc[5]);
      acc[6] = fmaf(wgt, (float)((q.y >> 16) & 0xffu), acc[6]);
      acc[7] = fmaf(wgt, (float)(q.y >> 24),           acc[7]);
    }
  }
#pragma unroll
  for (int k = 0; k < 4; ++k)
#pragma unroll
    for (int m = 1; m < 64; m <<= 1) den4[k] += __shfl_xor(den4[k], m);
  const float r = 1.f / (den4[hg] + EPS);
  const float corr = 128.f * sw;
#pragma unroll
  for (int i = 0; i < 8; ++i) acc[i] = (acc[i] - corr) * r;
#pragma unroll
  for (int i = 0; i < 8; ++i) {
    acc[i] += __shfl_xor(acc[i], 16);
    acc[i] += __shfl_xor(acc[i], 32);
  }
  if (lane < 16) {
    const int base = ((lane >> 3) & 1) * 64 + ((lane & 7) << 1);
#pragma unroll
    for (int k = 0; k < 4; ++k) {
      const float2 b2 = *(const float2*)&bias[base + k * 16];
      *(float2*)&out[(size_t)n * F_OUT + base + k * 16] =
          make_float2(0.25f * acc[k] + b2.x, 0.25f * acc[k + 4] + b2.y);
    }
  }
}

// ---------------- launch -------------------------------------------------------
extern "C" void kernel_launch(void* const* d_in, const int* in_sizes, int n_in,
                              void* d_out, int out_size, void* d_ws, size_t ws_size,
                              hipStream_t stream) {
  const float* H    = (const float*)d_in[0];
  const int*   ei   = (const int*)d_in[1];
  const float* W    = (const float*)d_in[2];   // [4,128,256] == [512,256]
  const float* a    = (const float*)d_in[3];   // [4,256]
  const float* bias = (const float*)d_in[4];   // [128]
  const int N = in_sizes[0] / F_IN;
  const int E = in_sizes[1] / 2;
  const int* src = ei;
  const int* dst = ei + E;

  const int RNG  = ((((N + 3) >> 2) + 7) & ~7);  // 12504 for N=50000 (<=12544)
  const int Npad = RNG * 4;
  const int nscan = (N + 255) / 256;

  char* ws = (char*)d_ws;
  size_t o = 0;
  auto alloc = [&](size_t bytes) -> void* {
    void* p = ws + o;
    o = (o + bytes + 255) & ~(size_t)255;
    return p;
  };
  unsigned char*  Hq  = (unsigned char*)alloc((size_t)N * COLS);          // 25.6 MB
  float* ssrc = (float*)alloc((size_t)N * HEADS * sizeof(float));
  unsigned char* rec = (unsigned char*)alloc((size_t)N * 32);             // 1.6 MB
  int*   cnt  = (int*)alloc((size_t)N * sizeof(int));
  int*   off  = (int*)alloc(((size_t)N + 1) * sizeof(int));
  unsigned short* csr  = (unsigned short*)alloc((size_t)E * sizeof(unsigned short));
  unsigned short* bcnt = (unsigned short*)alloc((size_t)NCH * Npad * 2);  // 6.4 MB
  unsigned int*  base  = (unsigned int*)alloc((size_t)NCH * Npad * 4);    // 12.8 MB
  int*   bsum = (int*)alloc((size_t)nscan * sizeof(int));

  const int Tg = 4 * ((N + 127) / 128);
  const int c0 = (Tg + 3) / 4;
  const int starts[4] = {0, c0, 2 * c0, 3 * c0};
  const int lens[4]   = {c0, c0, c0, Tg - 3 * c0};

  // L1: histogram (256 role blocks) + gemm chunk 0
  k_merged<<<256 + lens[0], 256, 0, stream>>>(0, 256, starts[0], lens[0],
      H, W, Hq, rec, ssrc, a, N, src, bcnt, cnt, bsum, off, base, E, RNG, Npad, nscan);
  // L2: colsum+scan1 + gemm chunk 1
  k_merged<<<nscan + lens[1], 256, 0, stream>>>(1, nscan, starts[1], lens[1],
      H, W, Hq, rec, ssrc, a, N, src, bcnt, cnt, bsum, off, base, E, RNG, Npad, nscan);
  // L3: scan3 + gemm chunk 2
  k_merged<<<nscan + lens[2], 256, 0, stream>>>(2, nscan, starts[2], lens[2],
      H, W, Hq, rec, ssrc, a, N, src, bcnt, cnt, bsum, off, base, E, RNG, Npad, nscan);
  // L4: base32 + gemm chunk 3
  k_merged<<<nscan + lens[3], 256, 0, stream>>>(3, nscan, starts[3], lens[3],
      H, W, Hq, rec, ssrc, a, N, src, bcnt, cnt, bsum, off, base, E, RNG, Npad, nscan);

  k_place<<<256, 256, 0, stream>>>(src, dst, base, csr, E, RNG, Npad);
  k_spmm<<<(N + 3) / 4, 256, 0, stream>>>((const uint2*)Hq, (const float4*)ssrc,
                                          rec, off, csr, bias, (float*)d_out, N);
}

// Round 18
// 303.545 us; speedup vs baseline: 1.0648x; 1.0648x over previous
//
#include <hip/hip_runtime.h>

#define ALPHA 0.2f
#define EPS 1e-16f

static constexpr int F_IN = 256;
static constexpr int F_OUT = 128;
static constexpr int HEADS = 4;
static constexpr int COLS = HEADS * F_OUT; // 512
static constexpr int NCH = 64;             // edge chunks in counting sort

typedef __bf16 bf16x8 __attribute__((ext_vector_type(8)));
typedef float f32x4 __attribute__((ext_vector_type(4)));

static __device__ __forceinline__ unsigned short f2bf(float f) {
  unsigned int u = __float_as_uint(f);
  unsigned int r = (u + 0x7FFFu + ((u >> 16) & 1u)) >> 16;  // RN-even
  return (unsigned short)r;
}
static __device__ __forceinline__ float bf_lo(unsigned int u) {
  return __uint_as_float(u << 16);
}
static __device__ __forceinline__ float bf_hi(unsigned int u) {
  return __uint_as_float(u & 0xFFFF0000u);
}
static __device__ __forceinline__ void cvt8(const float4& p0, const float4& p1, bf16x8& v) {
  v[0] = (__bf16)p0.x; v[1] = (__bf16)p0.y; v[2] = (__bf16)p0.z; v[3] = (__bf16)p0.w;
  v[4] = (__bf16)p1.x; v[5] = (__bf16)p1.y; v[6] = (__bf16)p1.z; v[7] = (__bf16)p1.w;
}

// ---------------- L1: cnt-histogram blocks (<256) + WHOLE GEMM (rest) ---------
// cnt: 4 range-quarters x 64 edge-chunks, LDS-private histogram (no global atomics).
// GEMM: 128x128 MFMA, f32 A/W cast-in-staging, fused score + int8 quant epilogues.
// rec[n] (32B): bytes 0..15 = sdst (4 f32); bytes 16..31 = 8 bf16 scales.
// Hq row layout (per 64-col block b): u32 at byte 64b+4k holds cols {0,16,32,48}+k.
__global__ __launch_bounds__(256) void k_merged(
    const float* __restrict__ A, const float* __restrict__ Wf,
    unsigned char* __restrict__ Hq, unsigned char* __restrict__ rec,
    float* __restrict__ ssrc, const float* __restrict__ Av, int N, int Tg,
    const int* __restrict__ src, unsigned short* __restrict__ bcnt,
    int E, int RNG, int Npad) {
  __shared__ union {
    unsigned int bins[6272];                 // 25088 B (RNG <= 12544)
    struct { __bf16 As[128][40]; __bf16 Bs[128][40]; float sS[128]; float sD[128]; } g;
  } u;
  const int t = threadIdx.x;

  if ((int)blockIdx.x < 256) {
    // ---- cnt role: range-split LDS histogram, block = (rq, ec) ----
    const int ec = blockIdx.x & (NCH - 1), rq = blockIdx.x >> 6;
    const int r0 = rq * RNG;
    const int nw = RNG >> 1;
    for (int jj = t; jj < nw; jj += 256) u.bins[jj] = 0u;
    __syncthreads();
    const int CE = (E + NCH - 1) / NCH;
    const int i0 = ec * CE, i1 = min(E, i0 + CE);
    for (int i = i0 + t; i < i1; i += 256) {
      const unsigned us = (unsigned)(src[i] - r0);
      if (us < (unsigned)RNG) atomicAdd(&u.bins[us >> 1], 1u << ((us & 1) << 4));
    }
    __syncthreads();
    uint4* dv = (uint4*)(bcnt + (size_t)ec * Npad + r0);   // 16B-aligned (RNG%8==0)
    const uint4* sv = (const uint4*)u.bins;
    const int nv = RNG >> 3;
    for (int m = t; m < nv; m += 256) dv[m] = sv[m];
    return;
  }

  // ================= GEMM role (whole gemm in this launch) =================
  const int j = (int)blockIdx.x - 256;
  const int q8 = Tg >> 3, r8 = Tg & 7;
  const int x = j & 7, ii = j >> 3;
  const int gp = (x < r8) ? x * (q8 + 1) + ii
                          : r8 * (q8 + 1) + (x - r8) * q8 + ii;
  const int by = gp >> 2;                  // row-tile
  const int bx = gp & 3;                   // 128-col block == head
  const int w = t >> 6, l = t & 63;
  const int wr = w >> 1, wc = w & 1;       // 2x2 wave grid, each 64x64
  const int m0 = by << 7, n0 = bx << 7;
  const int lr = t >> 1, seg16 = (t & 1) << 4;   // staging: row 0..127, col 0/16
  int ar = m0 + lr; if (ar >= N) ar = N - 1;     // clamp; stores guarded
  const float* Ap = A + (size_t)ar * F_IN + seg16;
  const float* Wp = Wf + (size_t)(n0 + lr) * F_IN + seg16;
  f32x4 acc[4][4] = {};
  for (int k0 = 0; k0 < F_IN; k0 += 32) {
    const float4 f0 = *(const float4*)(Ap + k0);
    const float4 f1 = *(const float4*)(Ap + k0 + 4);
    const float4 f2 = *(const float4*)(Ap + k0 + 8);
    const float4 f3 = *(const float4*)(Ap + k0 + 12);
    const float4 g0 = *(const float4*)(Wp + k0);
    const float4 g1 = *(const float4*)(Wp + k0 + 4);
    const float4 g2 = *(const float4*)(Wp + k0 + 8);
    const float4 g3 = *(const float4*)(Wp + k0 + 12);
    bf16x8 v0, v1, u0, u1;
    cvt8(f0, f1, v0); cvt8(f2, f3, v1);
    cvt8(g0, g1, u0); cvt8(g2, g3, u1);
    __syncthreads();
    *(bf16x8*)&u.g.As[lr][seg16] = v0;  *(bf16x8*)&u.g.As[lr][seg16 + 8] = v1;
    *(bf16x8*)&u.g.Bs[lr][seg16] = u0;  *(bf16x8*)&u.g.Bs[lr][seg16 + 8] = u1;
    __syncthreads();
    const int kb = (l >> 4) << 3;
    bf16x8 af[4], bf_[4];
#pragma unroll
    for (int mi = 0; mi < 4; ++mi)
      af[mi] = *(const bf16x8*)&u.g.As[(wr << 6) + (mi << 4) + (l & 15)][kb];
#pragma unroll
    for (int ni = 0; ni < 4; ++ni)
      bf_[ni] = *(const bf16x8*)&u.g.Bs[(wc << 6) + (ni << 4) + (l & 15)][kb];
#pragma unroll
    for (int mi = 0; mi < 4; ++mi)
#pragma unroll
      for (int ni = 0; ni < 4; ++ni)
        acc[mi][ni] = __builtin_amdgcn_mfma_f32_16x16x32_bf16(af[mi], bf_[ni], acc[mi][ni], 0, 0, 0);
  }
  // ---- score epilogue: s_src/s_dst for head bx from f32 accumulators ----
  {
    float as_[4], ad_[4];
#pragma unroll
    for (int ni = 0; ni < 4; ++ni) {
      const int f = (wc << 6) + (ni << 4) + (l & 15);
      as_[ni] = Av[bx * 256 + f];
      ad_[ni] = Av[bx * 256 + 128 + f];
    }
#pragma unroll
    for (int mi = 0; mi < 4; ++mi)
#pragma unroll
      for (int r = 0; r < 4; ++r) {
        float ds_ = 0.f, dd_ = 0.f;
#pragma unroll
        for (int ni = 0; ni < 4; ++ni) {
          ds_ = fmaf(acc[mi][ni][r], as_[ni], ds_);
          dd_ = fmaf(acc[mi][ni][r], ad_[ni], dd_);
        }
#pragma unroll
        for (int m = 1; m < 16; m <<= 1) {
          ds_ += __shfl_xor(ds_, m);
          dd_ += __shfl_xor(dd_, m);
        }
        if (wc == 0 && (l & 15) == 0) {
          const int rl = (wr << 6) + (mi << 4) + ((l >> 4) << 2) + r;
          u.g.sS[rl] = ds_; u.g.sD[rl] = dd_;
        }
      }
    __syncthreads();
    if (wc == 1) {
#pragma unroll
      for (int mi = 0; mi < 4; ++mi)
#pragma unroll
        for (int r = 0; r < 4; ++r) {
          float ds_ = 0.f, dd_ = 0.f;
#pragma unroll
          for (int ni = 0; ni < 4; ++ni) {
            ds_ = fmaf(acc[mi][ni][r], as_[ni], ds_);
            dd_ = fmaf(acc[mi][ni][r], ad_[ni], dd_);
          }
#pragma unroll
          for (int m = 1; m < 16; m <<= 1) {
            ds_ += __shfl_xor(ds_, m);
            dd_ += __shfl_xor(dd_, m);
          }
          if ((l & 15) == 0) {
            const int rl = (wr << 6) + (mi << 4) + ((l >> 4) << 2) + r;
            const int row = m0 + rl;
            if (row < N) {
              ssrc[row * 4 + bx] = u.g.sS[rl] + ds_;
              *(float*)&rec[(size_t)row * 32 + (bx << 2)] = u.g.sD[rl] + dd_;
            }
          }
        }
    }
  }
  // ---- quant epilogue: per-row absmax per 64-col block, excess-128 int8 ----
  const int bxg = (bx << 1) + wc;          // global 64-col block 0..7
#pragma unroll
  for (int mi = 0; mi < 4; ++mi)
#pragma unroll
    for (int r = 0; r < 4; ++r) {
      float mx = 0.f;
#pragma unroll
      for (int ni = 0; ni < 4; ++ni) mx = fmaxf(mx, fabsf(acc[mi][ni][r]));
#pragma unroll
      for (int m = 1; m < 16; m <<= 1) mx = fmaxf(mx, __shfl_xor(mx, m));
      const int row = m0 + (wr << 6) + (mi << 4) + ((l >> 4) << 2) + r;
      if (row < N) {
        const float inv = (mx > 0.f) ? 127.f / mx : 0.f;
        if ((l & 15) == 0)
          *(unsigned short*)&rec[(size_t)row * 32 + 16 + (bxg << 1)] = f2bf(mx * (1.f / 127.f));
        unsigned int pk = 0;
#pragma unroll
        for (int ni = 0; ni < 4; ++ni) {
          float tq = fminf(fmaxf(rintf(acc[mi][ni][r] * inv), -127.f), 127.f);
          pk |= ((unsigned int)(((int)tq + 128) & 255)) << (8 * ni);  // excess-128
        }
        *(unsigned int*)&Hq[(size_t)row * 512 + (bxg << 6) + ((l & 15) << 2)] = pk;
      }
    }
}

// ---------------- L2: colsum over 64 chunk-hists + block-local scan -----------
__global__ __launch_bounds__(256) void k_colsum_scan1(const unsigned short* __restrict__ bcnt,
                                                      int* __restrict__ cnt,
                                                      int* __restrict__ bsum, int N, int Npad) {
  __shared__ int ws[4];
  const int t = threadIdx.x, g = blockIdx.x * 256 + t;
  const int lane = t & 63, w = t >> 6;
  int v = 0;
  if (g < N) {
#pragma unroll 8
    for (int b = 0; b < NCH; ++b) v += bcnt[(size_t)b * Npad + g];  // indep loads
  }
#pragma unroll
  for (int o = 1; o < 64; o <<= 1) {
    const int y = __shfl_up(v, o);
    if (lane >= o) v += y;
  }
  if (lane == 63) ws[w] = v;
  __syncthreads();
  if (t == 0) {
    int s = 0;
#pragma unroll
    for (int k = 0; k < 4; ++k) { s += ws[k]; ws[k] = s; }
  }
  __syncthreads();
  v += (w > 0) ? ws[w - 1] : 0;
  if (g < N) cnt[g] = v;                  // inclusive within 256-chunk
  if (t == 255) bsum[blockIdx.x] = v;
}

// ---------------- L3: carry scan of bsum -> off --------------------------------
__global__ __launch_bounds__(256) void k_scan3(const int* __restrict__ part,
                                               const int* __restrict__ bsum,
                                               int* __restrict__ off, int N, int nscan) {
  __shared__ int sbuf[256];
  const int t = threadIdx.x;
  if (t < 64) {
    int carry = 0;
    for (int base = 0; base < nscan; base += 64) {
      int v = (base + t < nscan) ? bsum[base + t] : 0;
#pragma unroll
      for (int o = 1; o < 64; o <<= 1) {
        const int y = __shfl_up(v, o);
        if (t >= o) v += y;
      }
      v += carry;
      if (base + t < nscan) sbuf[base + t] = v;
      carry = __shfl(v, 63);
    }
  }
  __syncthreads();
  const int g = blockIdx.x * 256 + t;
  if (g == 0) off[0] = 0;
  if (g < N) off[g + 1] = part[g] + (blockIdx.x ? sbuf[blockIdx.x - 1] : 0);
}

// ---------------- L4: absolute slot bases base32[ec][s] ------------------------
__global__ __launch_bounds__(256) void k_base32(const unsigned short* __restrict__ bcnt,
                                                const int* __restrict__ off,
                                                unsigned int* __restrict__ base32,
                                                int N, int Npad) {
  const int s = blockIdx.x * 256 + threadIdx.x;
  if (s >= N) return;
  unsigned int run = (unsigned int)off[s];
#pragma unroll 8
  for (int b = 0; b < NCH; ++b) {
    const size_t idx = (size_t)b * Npad + s;
    const unsigned int v = bcnt[idx];
    base32[idx] = run;
    run += v;
  }
}

// ---------------- L5: re-histogram + direct placement (no global atomics) ------
__global__ __launch_bounds__(256) void k_place(const int* __restrict__ src,
                                               const int* __restrict__ dst,
                                               const unsigned int* __restrict__ base32,
                                               unsigned short* __restrict__ csr,
                                               int E, int RNG, int Npad) {
  __shared__ unsigned int bins[6272];
  const int ec = blockIdx.x & (NCH - 1), rq = blockIdx.x >> 6;
  const int r0 = rq * RNG, t = threadIdx.x;
  const int nw = RNG >> 1;
  for (int jj = t; jj < nw; jj += 256) bins[jj] = 0u;
  __syncthreads();
  const unsigned int* brow = base32 + (size_t)ec * Npad;
  const int CE = (E + NCH - 1) / NCH;
  const int i0 = ec * CE, i1 = min(E, i0 + CE);
  for (int i = i0 + t; i < i1; i += 256) {
    const int s = src[i];
    const unsigned us = (unsigned)(s - r0);
    if (us < (unsigned)RNG) {
      const unsigned int old = atomicAdd(&bins[us >> 1], 1u << ((us & 1) << 4));
      const int local = (old >> ((us & 1) << 4)) & 0xffff;
      csr[brow[s] + local] = (unsigned short)dst[i];
    }
  }
}

// ---------------- L6: fused softmax + SpMM, excess-128 int8 -------------------
__global__ __launch_bounds__(256) void k_spmm(const uint2* __restrict__ Hq2,
    const float4* __restrict__ ssrc4, const unsigned char* __restrict__ rec,
    const int* __restrict__ off, const unsigned short* __restrict__ csr_dst,
    const float* __restrict__ bias, float* __restrict__ out, int N) {
  __shared__ float wbuf[4][8][72];   // [wave][col-block][edge], w[h]*scl[d][b]
  __shared__ int   ibuf[4][64];
  const int wv = threadIdx.x >> 6;
  const int lane = threadIdx.x & 63;
  const int n = (blockIdx.x << 2) + wv;
  if (n >= N) return;                 // wave-private LDS, no barriers
  const int hg = lane >> 4;           // head of this lane
  const int b8 = lane >> 3;           // 64-col block of this lane
  const float4 ss4 = ssrc4[n];
  float den4[4] = {};
  float acc[8] = {};
  float sw = 0.f;                     // sum of this lane's scaled weights
  const int beg = off[n], end = off[n + 1];
  for (int c0 = beg; c0 < end; c0 += 64) {
    const int cnt = min(64, end - c0);
    if (lane < cnt) {                 // -------- phase A --------
      const int d = csr_dst[c0 + lane];          // coalesced u16
      ibuf[wv][lane] = d << 6;                   // row base in uint2 units
      const float4 sd4 = *(const float4*)&rec[(size_t)d * 32];       // one line:
      const uint4  sc  = *(const uint4*)&rec[(size_t)d * 32 + 16];   // sdst+scales
      float e0 = ss4.x + sd4.x; e0 = fmaxf(e0, ALPHA * e0);
      float e1 = ss4.y + sd4.y; e1 = fmaxf(e1, ALPHA * e1);
      float e2 = ss4.z + sd4.z; e2 = fmaxf(e2, ALPHA * e2);
      float e3 = ss4.w + sd4.w; e3 = fmaxf(e3, ALPHA * e3);
      const float w0 = __expf(e0), w1 = __expf(e1), w2 = __expf(e2), w3 = __expf(e3);
      den4[0] += w0; den4[1] += w1; den4[2] += w2; den4[3] += w3;
      wbuf[wv][0][lane] = w0 * bf_lo(sc.x); wbuf[wv][1][lane] = w0 * bf_hi(sc.x);
      wbuf[wv][2][lane] = w1 * bf_lo(sc.y); wbuf[wv][3][lane] = w1 * bf_hi(sc.y);
      wbuf[wv][4][lane] = w2 * bf_lo(sc.z); wbuf[wv][5][lane] = w2 * bf_hi(sc.z);
      wbuf[wv][6][lane] = w3 * bf_lo(sc.w); wbuf[wv][7][lane] = w3 * bf_hi(sc.w);
    }
#pragma unroll 8
    for (int j = 0; j < cnt; ++j) {   // -------- phase B --------
      const float wgt = wbuf[wv][b8][j];         // LDS broadcast (scaled)
      const int db = ibuf[wv][j];                // LDS broadcast
      const uint2 q = Hq2[db + lane];            // 8B gather, 512B/row/wave
      sw += wgt;
      acc[0] = fmaf(wgt, (float)(q.x & 0xffu),         acc[0]);
      acc[1] = fmaf(wgt, (float)((q.x >> 8) & 0xffu),  acc[1]);
      acc[2] = fmaf(wgt, (float)((q.x >> 16) & 0xffu), acc[2]);
      acc[3] = fmaf(wgt, (float)(q.x >> 24),           acc[3]);
      acc[4] = fmaf(wgt, (float)(q.y & 0xffu),         acc[4]);
      acc[5] = fmaf(wgt, (float)((q.y >> 8) & 0xffu),  acc[5]);
      acc[6] = fmaf(wgt, (float)((q.y >> 16) & 0xffu), acc[6]);
      acc[7] = fmaf(wgt, (float)(q.y >> 24),           acc[7]);
    }
  }
#pragma unroll
  for (int k = 0; k < 4; ++k)
#pragma unroll
    for (int m = 1; m < 64; m <<= 1) den4[k] += __shfl_xor(den4[k], m);
  const float r = 1.f / (den4[hg] + EPS);
  const float corr = 128.f * sw;      // undo excess-128 bias
#pragma unroll
  for (int i = 0; i < 8; ++i) acc[i] = (acc[i] - corr) * r;
#pragma unroll
  for (int i = 0; i < 8; ++i) {       // sum the 4 heads (same feature at l^16,l^32)
    acc[i] += __shfl_xor(acc[i], 16);
    acc[i] += __shfl_xor(acc[i], 32);
  }
  if (lane < 16) {
    // permuted layout: acc[i] = feature 64*((lane>>3)&1) + (i&3)*16 + 2*(lane&7) + (i>>2)
    const int base = ((lane >> 3) & 1) * 64 + ((lane & 7) << 1);
#pragma unroll
    for (int k = 0; k < 4; ++k) {
      const float2 b2 = *(const float2*)&bias[base + k * 16];
      *(float2*)&out[(size_t)n * F_OUT + base + k * 16] =
          make_float2(0.25f * acc[k] + b2.x, 0.25f * acc[k + 4] + b2.y);
    }
  }
}

// ---------------- launch -------------------------------------------------------
extern "C" void kernel_launch(void* const* d_in, const int* in_sizes, int n_in,
                              void* d_out, int out_size, void* d_ws, size_t ws_size,
                              hipStream_t stream) {
  const float* H    = (const float*)d_in[0];
  const int*   ei   = (const int*)d_in[1];
  const float* W    = (const float*)d_in[2];   // [4,128,256] == [512,256]
  const float* a    = (const float*)d_in[3];   // [4,256]
  const float* bias = (const float*)d_in[4];   // [128]
  const int N = in_sizes[0] / F_IN;
  const int E = in_sizes[1] / 2;
  const int* src = ei;
  const int* dst = ei + E;

  const int RNG  = ((((N + 3) >> 2) + 7) & ~7);  // 12504 for N=50000 (<=12544)
  const int Npad = RNG * 4;                      // 50016
  const int nscan = (N + 255) / 256;             // 196

  char* ws = (char*)d_ws;
  size_t o = 0;
  auto alloc = [&](size_t bytes) -> void* {
    void* p = ws + o;
    o = (o + bytes + 255) & ~(size_t)255;
    return p;
  };
  unsigned char*  Hq  = (unsigned char*)alloc((size_t)N * COLS);          // 25.6 MB
  float* ssrc = (float*)alloc((size_t)N * HEADS * sizeof(float));
  unsigned char* rec = (unsigned char*)alloc((size_t)N * 32);             // 1.6 MB
  int*   cnt  = (int*)alloc((size_t)N * sizeof(int));
  int*   off  = (int*)alloc(((size_t)N + 1) * sizeof(int));
  unsigned short* csr  = (unsigned short*)alloc((size_t)E * sizeof(unsigned short));
  unsigned short* bcnt = (unsigned short*)alloc((size_t)NCH * Npad * 2);  // 6.4 MB
  unsigned int*  base  = (unsigned int*)alloc((size_t)NCH * Npad * 4);    // 12.8 MB
  int*   bsum = (int*)alloc((size_t)nscan * sizeof(int));

  const int Tg = 4 * ((N + 127) / 128);   // 1564

  // L1: cnt histogram (256 blocks) + WHOLE gemm (Tg blocks) in one dispatch
  k_merged<<<256 + Tg, 256, 0, stream>>>(H, W, Hq, rec, ssrc, a, N, Tg,
                                         src, bcnt, E, RNG, Npad);
  k_colsum_scan1<<<nscan, 256, 0, stream>>>(bcnt, cnt, bsum, N, Npad);
  k_scan3<<<nscan, 256, 0, stream>>>(cnt, bsum, off, N, nscan);
  k_base32<<<nscan, 256, 0, stream>>>(bcnt, off, base, N, Npad);
  k_place<<<256, 256, 0, stream>>>(src, dst, base, csr, E, RNG, Npad);
  k_spmm<<<(N + 3) / 4, 256, 0, stream>>>((const uint2*)Hq, (const float4*)ssrc,
                                          rec, off, csr, bias, (float*)d_out, N);
}